// Round 12
// baseline (348.636 us; speedup 1.0000x reference)
//
#include <hip/hip_runtime.h>
#include <hip/hip_fp16.h>

#define NN 100000
#define NE 1600000
#define BK 512           // nodes per bucket
#define BKSH 9           // log2(BK)
#define NBKT 196         // ceil(NN/BK)
#define SLOT 9216        // fixed edge capacity per bucket (mean 8192, sigma~90)
#define SRCMASK 0x1FFFF  // 17 bits (NN < 131072)

typedef _Float16 half2v __attribute__((ext_vector_type(2)));

__device__ inline float dot2acc(unsigned int a, unsigned int b, float c) {
#if __has_builtin(__builtin_amdgcn_fdot2)
    union { unsigned int u; half2v h; } ua, ub;
    ua.u = a; ub.u = b;
    return __builtin_amdgcn_fdot2(ua.h, ub.h, c, false);
#else
    float2 fa = __half22float2(*(const __half2*)&a);
    float2 fb = __half22float2(*(const __half2*)&b);
    return c + fa.x * fb.x + fa.y * fb.y;
#endif
}

__device__ inline int wave_incl_scan(int v, int lane) {
#pragma unroll
    for (int off = 1; off < 64; off <<= 1) {
        int t = __shfl_up(v, off, 64);
        if (lane >= off) v += t;
    }
    return v;
}

// ---------------- CSR build: fixed-slot buckets ----------------

__global__ __launch_bounds__(256) void zero_small_kernel(int* __restrict__ p, int n) {
    int i = threadIdx.x + blockIdx.x * 256;
    if (i < n) p[i] = 0;
}

// 4096-edge tiles, 512 threads. Per-tile LDS hist + single-wave scan over the
// 196 buckets, LDS reorder, near-coalesced copy-out into fixed bucket slots.
__global__ __launch_bounds__(512) void bscatter_kernel(const int* __restrict__ src,
                                                       const int* __restrict__ dst,
                                                       int* __restrict__ bcur,
                                                       unsigned int* __restrict__ bedges,
                                                       int e) {
    __shared__ int h[256];
    __shared__ int sc[256];
    __shared__ int gb[256];
    __shared__ int2 stg[4096];   // {packed, bucket}
    int tid = threadIdx.x;
    int tile = blockIdx.x * 4096;
    int cnt_tile = min(4096, e - tile);
    if (tid < 256) h[tid] = 0;
    __syncthreads();
    unsigned int pk[8]; int rk[8], bk[8];
#pragma unroll
    for (int j = 0; j < 8; j++) {
        int li = tid + j * 512;
        if (li < cnt_tile) {
            int s = src[tile + li];
            int d = dst[tile + li];
            bk[j] = d >> BKSH;
            pk[j] = ((unsigned)(d & (BK - 1)) << 17) | (unsigned)s;
            rk[j] = atomicAdd(&h[bk[j]], 1);
        } else bk[j] = -1;
    }
    __syncthreads();
    if (tid < 64) {   // single-wave scan: 4 buckets/lane
        int b0 = tid * 4;
        int c0 = h[b0], c1 = h[b0 + 1], c2 = h[b0 + 2], c3 = h[b0 + 3];
        int s4 = c0 + c1 + c2 + c3;
        int incl = wave_incl_scan(s4, tid);
        int base = incl - s4;
        sc[b0] = base; sc[b0 + 1] = base + c0;
        sc[b0 + 2] = base + c0 + c1; sc[b0 + 3] = base + c0 + c1 + c2;
        if (c0) gb[b0] = atomicAdd(&bcur[b0], c0);
        if (c1) gb[b0 + 1] = atomicAdd(&bcur[b0 + 1], c1);
        if (c2) gb[b0 + 2] = atomicAdd(&bcur[b0 + 2], c2);
        if (c3) gb[b0 + 3] = atomicAdd(&bcur[b0 + 3], c3);
    }
    __syncthreads();
#pragma unroll
    for (int j = 0; j < 8; j++)
        if (bk[j] >= 0) stg[sc[bk[j]] + rk[j]] = make_int2((int)pk[j], bk[j]);
    __syncthreads();
#pragma unroll
    for (int j = 0; j < 8; j++) {
        int li = tid + j * 512;
        if (li < cnt_tile) {
            int2 p2 = stg[li];
            int b = p2.y;
            bedges[(size_t)b * SLOT + gb[b] + (li - sc[b])] = (unsigned int)p2.x;
        }
    }
}

// One 1024-thread block per bucket: LDS hist + single-wave scan + cursor
// scatter + (fused) prep of g0 = fp16(dinv .* x) for this bucket's nodes.
__global__ __launch_bounds__(1024) void bfill_kernel(const unsigned int* __restrict__ bedges,
                                                     const int* __restrict__ bcur,
                                                     const float* __restrict__ x,
                                                     int* __restrict__ start,
                                                     int* __restrict__ cnt,
                                                     float* __restrict__ dinv,
                                                     int* __restrict__ csr,
                                                     __half* __restrict__ g0) {
    __shared__ int lcnt[BK];
    __shared__ int lstart[BK];
    __shared__ int lcur[BK];
    int q = blockIdx.x, tid = threadIdx.x;
    size_t ebase = (size_t)q * SLOT;
    int ec = bcur[q];
    int nbase = q * BK;
    if (tid < BK) lcnt[tid] = 0;
    __syncthreads();
    for (int i = tid; i < ec; i += 1024)
        atomicAdd(&lcnt[__builtin_nontemporal_load(&bedges[ebase + i]) >> 17], 1);
    __syncthreads();
    if (tid < 64) {   // single-wave scan: 8 buckets/lane
        int b0 = tid * 8;
        int c[8]; int s = 0;
#pragma unroll
        for (int k = 0; k < 8; k++) { c[k] = lcnt[b0 + k]; s += c[k]; }
        int incl = wave_incl_scan(s, tid);
        int run = incl - s;
#pragma unroll
        for (int k = 0; k < 8; k++) { lstart[b0 + k] = run; lcur[b0 + k] = run; run += c[k]; }
    }
    __syncthreads();
    if (tid < BK) {
        int nd = nbase + tid;
        if (nd < NN) {
            start[nd] = (int)ebase + lstart[tid];
            cnt[nd]   = lcnt[tid];
            dinv[nd]  = rsqrtf((float)lcnt[tid] + 1.0f);
        }
    }
    for (int i = tid; i < ec; i += 1024) {
        unsigned int pk = __builtin_nontemporal_load(&bedges[ebase + i]);
        int r = atomicAdd(&lcur[pk >> 17], 1);
        csr[ebase + r] = (int)(pk & SRCMASK);
    }
    // fused prep: g0 rows for this bucket (lcnt stable since its barrier)
    for (int i = tid; i < BK * 16; i += 1024) {   // 16 float4 per row
        int l = i >> 4, c4 = (i & 15) * 4;
        int nd = nbase + l;
        if (nd < NN) {
            float dv = rsqrtf((float)lcnt[l] + 1.0f);
            float4 v = *(const float4*)&x[(size_t)nd * 64 + c4];
            __half2 h01 = __floats2half2_rn(v.x * dv, v.y * dv);
            __half2 h23 = __floats2half2_rn(v.z * dv, v.w * dv);
            __half2* gp = (__half2*)&g0[(size_t)nd * 64 + c4];
            gp[0] = h01;
            gp[1] = h23;
        }
    }
}

// ---------------- Fused layer (1-3): gather + 64x64 transform ----------------
// 1 node/wave, no post-gather barrier, 16-deep gather unroll for MLP.
__global__ __launch_bounds__(512) void fused_layer_kernel(const __half* __restrict__ g,
                                                          const int* __restrict__ csr,
                                                          const int* __restrict__ start,
                                                          const int* __restrict__ cnt,
                                                          const float* __restrict__ dinv,
                                                          const float* __restrict__ Wg,
                                                          const float* __restrict__ bias,
                                                          __half* __restrict__ gout, int n) {
    __shared__ uint4 wpk[8][64];   // 8KB: wpk[p][c] = half W[8p..8p+7][c]
    __shared__ __half zh[8][64];   // 1KB, one row per wave
    __shared__ float bs[64];
    int tid = threadIdx.x;
    {
        int p = tid >> 6, c = tid & 63;
        float w[8];
#pragma unroll
        for (int i = 0; i < 8; i++) w[i] = Wg[(8 * p + i) * 64 + c];
        union { __half2 h; unsigned int u; } u0, u1, u2, u3;
        u0.h = __floats2half2_rn(w[0], w[1]);
        u1.h = __floats2half2_rn(w[2], w[3]);
        u2.h = __floats2half2_rn(w[4], w[5]);
        u3.h = __floats2half2_rn(w[6], w[7]);
        wpk[p][c] = make_uint4(u0.u, u1.u, u2.u, u3.u);
    }
    if (tid < 64) bs[tid] = bias[tid];
    __syncthreads();   // only barrier: W/bias staging

    int wv = tid >> 6, lane = tid & 63;
    int node = blockIdx.x * 8 + wv;
    float acc = 0.f;
    float dv = 0.f;
    if (node < n) {
        int st = __builtin_amdgcn_readfirstlane(start[node]);
        int cn = __builtin_amdgcn_readfirstlane(cnt[node]);
        dv = dinv[node];
        acc = __half2float(g[(size_t)node * 64 + lane]);  // self loop
        int e = 0;
        for (; e + 15 < cn; e += 16) {   // 16-deep independent window
            int u[16]; float a[16];
#pragma unroll
            for (int j = 0; j < 16; j++) u[j] = __builtin_nontemporal_load(&csr[st + e + j]);
#pragma unroll
            for (int j = 0; j < 16; j++) a[j] = __half2float(g[(size_t)u[j] * 64 + lane]);
            float s0 = ((a[0] + a[1]) + (a[2] + a[3])) + ((a[4] + a[5]) + (a[6] + a[7]));
            float s1 = ((a[8] + a[9]) + (a[10] + a[11])) + ((a[12] + a[13]) + (a[14] + a[15]));
            acc += s0 + s1;
        }
        for (; e + 7 < cn; e += 8) {
            int u[8]; float a[8];
#pragma unroll
            for (int j = 0; j < 8; j++) u[j] = __builtin_nontemporal_load(&csr[st + e + j]);
#pragma unroll
            for (int j = 0; j < 8; j++) a[j] = __half2float(g[(size_t)u[j] * 64 + lane]);
            acc += ((a[0] + a[1]) + (a[2] + a[3])) + ((a[4] + a[5]) + (a[6] + a[7]));
        }
        for (; e + 3 < cn; e += 4) {
            int u0 = __builtin_nontemporal_load(&csr[st + e + 0]);
            int u1 = __builtin_nontemporal_load(&csr[st + e + 1]);
            int u2 = __builtin_nontemporal_load(&csr[st + e + 2]);
            int u3 = __builtin_nontemporal_load(&csr[st + e + 3]);
            float a0 = __half2float(g[(size_t)u0 * 64 + lane]);
            float a1 = __half2float(g[(size_t)u1 * 64 + lane]);
            float a2 = __half2float(g[(size_t)u2 * 64 + lane]);
            float a3 = __half2float(g[(size_t)u3 * 64 + lane]);
            acc += (a0 + a1) + (a2 + a3);
        }
        for (; e < cn; e++) {
            int u = __builtin_nontemporal_load(&csr[st + e]);
            acc += __half2float(g[(size_t)u * 64 + lane]);
        }
    }
    zh[wv][lane] = __float2half_rn(acc);   // wave-private: no barrier
    if (node < n) {
        float t = 0.f;
#pragma unroll
        for (int p = 0; p < 8; p++) {
            uint4 wq = wpk[p][lane];                        // per-lane b128
            uint4 zq = *(const uint4*)&zh[wv][p * 8];       // uniform b128
            t = dot2acc(zq.x, wq.x, t);
            t = dot2acc(zq.y, wq.y, t);
            t = dot2acc(zq.z, wq.z, t);
            t = dot2acc(zq.w, wq.w, t);
        }
        float o = dv * t + bs[lane];
        o = fmaxf(o, 0.f);
        gout[(size_t)node * 64 + lane] = __float2half_rn(dv * o);
    }
}

// ---------------- Layer-4 transform: s4 = g3 @ W4  (dinv cancels exactly) ----------------
__global__ __launch_bounds__(128) void gemm16_kernel(const __half* __restrict__ xin,
                                                     const float* __restrict__ W,
                                                     __half* __restrict__ s, int n) {
    constexpr int DOUT = 16;
    constexpr int ROWS = 128;
    __shared__ float xs[ROWS][65];
    __shared__ float ws[64][DOUT];
    int tid = threadIdx.x;
    int row0 = blockIdx.x * ROWS;
    for (int i = tid; i < 64 * DOUT; i += 128) ws[i / DOUT][i % DOUT] = W[i];
    for (int i = tid; i < ROWS * 16; i += 128) {
        int r = i >> 4, c = (i & 15) * 4;
        float4 v = make_float4(0.f, 0.f, 0.f, 0.f);
        if (row0 + r < n) {
            const __half* hp = xin + (size_t)(row0 + r) * 64 + c;
            float2 f01 = __half22float2(*(const __half2*)hp);
            float2 f23 = __half22float2(*(const __half2*)(hp + 2));
            v = make_float4(f01.x, f01.y, f23.x, f23.y);
        }
        xs[r][c] = v.x; xs[r][c + 1] = v.y; xs[r][c + 2] = v.z; xs[r][c + 3] = v.w;
    }
    __syncthreads();
    int rbase = tid;
    float acc[16];
#pragma unroll
    for (int j = 0; j < 16; j++) acc[j] = 0.f;
    for (int k = 0; k < 64; k++) {
        float xv = xs[rbase][k];
#pragma unroll
        for (int j = 0; j < 4; j++) {
            float4 wv = *(const float4*)&ws[k][j * 4];
            acc[j * 4 + 0] += xv * wv.x;
            acc[j * 4 + 1] += xv * wv.y;
            acc[j * 4 + 2] += xv * wv.z;
            acc[j * 4 + 3] += xv * wv.w;
        }
    }
    int r = row0 + rbase;
    if (r < n) {
        union { ushort u[16]; uint4 q[2]; } pk;
#pragma unroll
        for (int j = 0; j < 16; j++)
            pk.u[j] = __half_as_ushort(__float2half_rn(acc[j]));
        uint4* sp = (uint4*)&s[(size_t)r * DOUT];
        sp[0] = pk.q[0];
        sp[1] = pk.q[1];
    }
}

// ---------------- Layer-4 aggregate: out = dinv*(sum s4) + b4, fp32 ----------------
__global__ __launch_bounds__(256) void agg16_kernel(const __half* __restrict__ s,
                                                    const int* __restrict__ csr,
                                                    const int* __restrict__ start,
                                                    const int* __restrict__ cnt,
                                                    const float* __restrict__ dinv,
                                                    const float* __restrict__ bias,
                                                    float* __restrict__ out, int n) {
    constexpr int D = 16;
    int tid = threadIdx.x;
    int lane = tid & 63;
    int wave = tid >> 6;
    int col = lane % D;
    int grp = lane / D;
    int node = (blockIdx.x * 4 + wave) * 4 + grp;
    if (node >= n) return;
    int st = start[node];
    int cn = cnt[node];
    float acc = __half2float(s[(size_t)node * D + col]);  // self loop
    int e = 0;
    for (; e + 7 < cn; e += 8) {
        int u[8]; float a[8];
#pragma unroll
        for (int j = 0; j < 8; j++) u[j] = __builtin_nontemporal_load(&csr[st + e + j]);
#pragma unroll
        for (int j = 0; j < 8; j++) a[j] = __half2float(s[(size_t)u[j] * D + col]);
        acc += ((a[0] + a[1]) + (a[2] + a[3])) + ((a[4] + a[5]) + (a[6] + a[7]));
    }
    for (; e + 3 < cn; e += 4) {
        int u0 = __builtin_nontemporal_load(&csr[st + e + 0]);
        int u1 = __builtin_nontemporal_load(&csr[st + e + 1]);
        int u2 = __builtin_nontemporal_load(&csr[st + e + 2]);
        int u3 = __builtin_nontemporal_load(&csr[st + e + 3]);
        float a0 = __half2float(s[(size_t)u0 * D + col]);
        float a1 = __half2float(s[(size_t)u1 * D + col]);
        float a2 = __half2float(s[(size_t)u2 * D + col]);
        float a3 = __half2float(s[(size_t)u3 * D + col]);
        acc += (a0 + a1) + (a2 + a3);
    }
    for (; e < cn; e++) {
        int u = __builtin_nontemporal_load(&csr[st + e]);
        acc += __half2float(s[(size_t)u * D + col]);
    }
    float o = dinv[node] * acc + bias[col];
    __builtin_nontemporal_store(o, out + (size_t)node * D + col);
}

// ---------------- launch ----------------

extern "C" void kernel_launch(void* const* d_in, const int* in_sizes, int n_in,
                              void* d_out, int out_size, void* d_ws, size_t ws_size,
                              hipStream_t stream) {
    const float* x  = (const float*)d_in[0];
    const int* ei   = (const int*)d_in[1];
    const float* W1 = (const float*)d_in[2];
    const float* b1 = (const float*)d_in[3];
    const float* W2 = (const float*)d_in[4];
    const float* b2 = (const float*)d_in[5];
    const float* W3 = (const float*)d_in[6];
    const float* b3 = (const float*)d_in[7];
    const float* W4 = (const float*)d_in[8];
    const float* b4 = (const float*)d_in[9];
    const int* src = ei;
    const int* dst = ei + NE;

    // all blocks 128B-aligned; g rows (128B) MUST be 128B-aligned: halves
    // gather line-sectors (R11 finding: FETCH 156->88MB from alignment alone)
    char* w = (char*)d_ws;
    auto alloc = [&](size_t bytes) {
        char* p = w;
        w += (bytes + 127) & ~(size_t)127;
        return p;
    };
    float* dinv  = (float*)alloc((size_t)NN * 4);
    int* cnt     = (int*)alloc((size_t)NN * 4);
    int* start   = (int*)alloc((size_t)NN * 4);
    int* bcur    = (int*)alloc(256 * 4);
    int* csr     = (int*)alloc((size_t)NBKT * SLOT * 4);
    __half* gA   = (__half*)alloc((size_t)NN * 64 * 2);
    __half* gB   = (__half*)alloc((size_t)NN * 64 * 2);
    __half* s4   = (__half*)alloc((size_t)NN * 16 * 2);
    unsigned int* bedges = (unsigned int*)alloc((size_t)NBKT * SLOT * 4);

    zero_small_kernel<<<1, 256, 0, stream>>>(bcur, 256);
    bscatter_kernel<<<(NE + 4095) / 4096, 512, 0, stream>>>(src, dst, bcur, bedges, NE);
    bfill_kernel<<<NBKT, 1024, 0, stream>>>(bedges, bcur, x, start, cnt, dinv, csr, gA);

    const int FB = (NN + 7) / 8;      // 12500 blocks, 1 node/wave
    fused_layer_kernel<<<FB, 512, 0, stream>>>(gA, csr, start, cnt, dinv, W1, b1, gB, NN);
    fused_layer_kernel<<<FB, 512, 0, stream>>>(gB, csr, start, cnt, dinv, W2, b2, gA, NN);
    fused_layer_kernel<<<FB, 512, 0, stream>>>(gA, csr, start, cnt, dinv, W3, b3, gB, NN);

    const int GB = (NN + 127) / 128;
    const int AB16 = (NN + 15) / 16;
    gemm16_kernel<<<GB, 128, 0, stream>>>(gB, W4, s4, NN);
    agg16_kernel<<<AB16, 256, 0, stream>>>(s4, csr, start, cnt, dinv, b4, (float*)d_out, NN);
}

// Round 13
// 340.155 us; speedup vs baseline: 1.0249x; 1.0249x over previous
//
#include <hip/hip_runtime.h>
#include <hip/hip_fp16.h>

#define NN 100000
#define NE 1600000
#define BK 512           // nodes per bucket
#define BKSH 9           // log2(BK)
#define NBKT 196         // ceil(NN/BK)
#define SLOT 9216        // fixed edge capacity per bucket (mean 8192, sigma~90)
#define SRCMASK 0x1FFFF  // 17 bits (NN < 131072)

typedef _Float16 half2v __attribute__((ext_vector_type(2)));

__device__ inline float dot2acc(unsigned int a, unsigned int b, float c) {
#if __has_builtin(__builtin_amdgcn_fdot2)
    union { unsigned int u; half2v h; } ua, ub;
    ua.u = a; ub.u = b;
    return __builtin_amdgcn_fdot2(ua.h, ub.h, c, false);
#else
    float2 fa = __half22float2(*(const __half2*)&a);
    float2 fb = __half22float2(*(const __half2*)&b);
    return c + fa.x * fb.x + fa.y * fb.y;
#endif
}

__device__ inline int wave_incl_scan(int v, int lane) {
#pragma unroll
    for (int off = 1; off < 64; off <<= 1) {
        int t = __shfl_up(v, off, 64);
        if (lane >= off) v += t;
    }
    return v;
}

// ---------------- CSR build: fixed-slot buckets ----------------

__global__ __launch_bounds__(256) void zero_small_kernel(int* __restrict__ p, int n) {
    int i = threadIdx.x + blockIdx.x * 256;
    if (i < n) p[i] = 0;
}

// 4096-edge tiles, 512 threads. Per-WAVE hists kill inter-wave LDS-atomic
// same-address serialization; ranks combine via per-bucket cross-wave prefix.
__global__ __launch_bounds__(512) void bscatter_kernel(const int* __restrict__ src,
                                                       const int* __restrict__ dst,
                                                       int* __restrict__ bcur,
                                                       unsigned int* __restrict__ bedges,
                                                       int e) {
    __shared__ int h[8][256];    // per-wave hist -> becomes per-wave exclusive base
    __shared__ int tot[256];
    __shared__ int sc[256];
    __shared__ int gb[256];
    __shared__ int2 stg[4096];   // {packed, bucket}
    int tid = threadIdx.x, wv = tid >> 6;
    int tile = blockIdx.x * 4096;
    int cnt_tile = min(4096, e - tile);
    for (int i = tid; i < 8 * 256; i += 512) ((int*)h)[i] = 0;
    __syncthreads();
    unsigned int pk[8]; int rk[8], bk[8];
#pragma unroll
    for (int j = 0; j < 8; j++) {
        int li = tid + j * 512;
        if (li < cnt_tile) {
            int s = src[tile + li];
            int d = dst[tile + li];
            bk[j] = d >> BKSH;
            pk[j] = ((unsigned)(d & (BK - 1)) << 17) | (unsigned)s;
            rk[j] = atomicAdd(&h[wv][bk[j]], 1);   // wave-private: rare collisions
        } else bk[j] = -1;
    }
    __syncthreads();
    if (tid < 256) {   // cross-wave prefix per bucket; h becomes per-wave base
        int run = 0;
#pragma unroll
        for (int w = 0; w < 8; w++) { int c = h[w][tid]; h[w][tid] = run; run += c; }
        tot[tid] = run;
    }
    __syncthreads();
    if (tid < 64) {    // single-wave scan over buckets: 4/lane
        int b0 = tid * 4;
        int c0 = tot[b0], c1 = tot[b0 + 1], c2 = tot[b0 + 2], c3 = tot[b0 + 3];
        int s4 = c0 + c1 + c2 + c3;
        int incl = wave_incl_scan(s4, tid);
        int base = incl - s4;
        sc[b0] = base; sc[b0 + 1] = base + c0;
        sc[b0 + 2] = base + c0 + c1; sc[b0 + 3] = base + c0 + c1 + c2;
        if (c0) gb[b0] = atomicAdd(&bcur[b0], c0);
        if (c1) gb[b0 + 1] = atomicAdd(&bcur[b0 + 1], c1);
        if (c2) gb[b0 + 2] = atomicAdd(&bcur[b0 + 2], c2);
        if (c3) gb[b0 + 3] = atomicAdd(&bcur[b0 + 3], c3);
    }
    __syncthreads();
#pragma unroll
    for (int j = 0; j < 8; j++)
        if (bk[j] >= 0) stg[sc[bk[j]] + h[wv][bk[j]] + rk[j]] = make_int2((int)pk[j], bk[j]);
    __syncthreads();
#pragma unroll
    for (int j = 0; j < 8; j++) {
        int li = tid + j * 512;
        if (li < cnt_tile) {
            int2 p2 = stg[li];
            int b = p2.y;
            bedges[(size_t)b * SLOT + gb[b] + (li - sc[b])] = (unsigned int)p2.x;
        }
    }
}

// One 1024-thread block per bucket. Single atomic pass: ranks captured into
// 4 group-private sub-hists during the hist; cursor-scatter pass deleted.
// Also emits g0 = fp16(dinv .* x) for this bucket's nodes (fused prep).
__global__ __launch_bounds__(1024) void bfill_kernel(const unsigned int* __restrict__ bedges,
                                                     const int* __restrict__ bcur,
                                                     const float* __restrict__ x,
                                                     int* __restrict__ start,
                                                     int* __restrict__ cnt,
                                                     float* __restrict__ dinv,
                                                     int* __restrict__ csr,
                                                     __half* __restrict__ g0) {
    __shared__ int sub[4][BK];   // 8KB: group hists -> group exclusive bases
    __shared__ int lcnt[BK];
    __shared__ int lstart[BK];
    int q = blockIdx.x, tid = threadIdx.x;
    int grp = (tid >> 6) >> 2;   // 16 waves -> 4 groups
    size_t ebase = (size_t)q * SLOT;
    int ec = bcur[q];
    int nbase = q * BK;
    for (int i = tid; i < 4 * BK; i += 1024) ((int*)sub)[i] = 0;
    __syncthreads();
    unsigned int pk[9]; int rk[9];
    int nit = 0;
    for (int i = tid; i < ec; i += 1024) {
        pk[nit] = __builtin_nontemporal_load(&bedges[ebase + i]);
        rk[nit] = atomicAdd(&sub[grp][pk[nit] >> 17], 1);
        nit++;
    }
    __syncthreads();
    if (tid < BK) {   // cross-group prefix per node; sub becomes group base
        int run = 0;
#pragma unroll
        for (int g = 0; g < 4; g++) { int c = sub[g][tid]; sub[g][tid] = run; run += c; }
        lcnt[tid] = run;
    }
    __syncthreads();
    if (tid < 64) {   // single-wave scan: 8 nodes/lane
        int b0 = tid * 8;
        int c[8]; int s = 0;
#pragma unroll
        for (int k = 0; k < 8; k++) { c[k] = lcnt[b0 + k]; s += c[k]; }
        int incl = wave_incl_scan(s, tid);
        int run = incl - s;
#pragma unroll
        for (int k = 0; k < 8; k++) { lstart[b0 + k] = run; run += c[k]; }
    }
    __syncthreads();
    if (tid < BK) {
        int nd = nbase + tid;
        if (nd < NN) {
            start[nd] = (int)ebase + lstart[tid];
            cnt[nd]   = lcnt[tid];
            dinv[nd]  = rsqrtf((float)lcnt[tid] + 1.0f);
        }
    }
    // atomic-free scatter using captured ranks
    for (int it = 0, i = tid; it < nit; it++, i += 1024) {
        int d = pk[it] >> 17;
        csr[ebase + lstart[d] + sub[grp][d] + rk[it]] = (int)(pk[it] & SRCMASK);
    }
    // fused prep: g0 rows for this bucket
    for (int i = tid; i < BK * 16; i += 1024) {   // 16 float4 per row
        int l = i >> 4, c4 = (i & 15) * 4;
        int nd = nbase + l;
        if (nd < NN) {
            float dv = rsqrtf((float)lcnt[l] + 1.0f);
            float4 v = *(const float4*)&x[(size_t)nd * 64 + c4];
            __half2 h01 = __floats2half2_rn(v.x * dv, v.y * dv);
            __half2 h23 = __floats2half2_rn(v.z * dv, v.w * dv);
            __half2* gp = (__half2*)&g0[(size_t)nd * 64 + c4];
            gp[0] = h01;
            gp[1] = h23;
        }
    }
}

// ---------------- Fused layer (1-3): gather + 64x64 transform (R11 body) ----------------
__global__ __launch_bounds__(512) void fused_layer_kernel(const __half* __restrict__ g,
                                                          const int* __restrict__ csr,
                                                          const int* __restrict__ start,
                                                          const int* __restrict__ cnt,
                                                          const float* __restrict__ dinv,
                                                          const float* __restrict__ Wg,
                                                          const float* __restrict__ bias,
                                                          __half* __restrict__ gout, int n) {
    __shared__ uint4 wpk[8][64];   // 8KB: wpk[p][c] = half W[8p..8p+7][c]
    __shared__ __half zh[8][64];   // 1KB, one row per wave
    __shared__ float bs[64];
    int tid = threadIdx.x;
    {
        int p = tid >> 6, c = tid & 63;
        float w[8];
#pragma unroll
        for (int i = 0; i < 8; i++) w[i] = Wg[(8 * p + i) * 64 + c];
        union { __half2 h; unsigned int u; } u0, u1, u2, u3;
        u0.h = __floats2half2_rn(w[0], w[1]);
        u1.h = __floats2half2_rn(w[2], w[3]);
        u2.h = __floats2half2_rn(w[4], w[5]);
        u3.h = __floats2half2_rn(w[6], w[7]);
        wpk[p][c] = make_uint4(u0.u, u1.u, u2.u, u3.u);
    }
    if (tid < 64) bs[tid] = bias[tid];
    __syncthreads();   // only barrier: W/bias staging

    int wv = tid >> 6, lane = tid & 63;
    int node = blockIdx.x * 8 + wv;
    float acc = 0.f;
    float dv = 0.f;
    if (node < n) {
        int st = __builtin_amdgcn_readfirstlane(start[node]);
        int cn = __builtin_amdgcn_readfirstlane(cnt[node]);
        dv = dinv[node];
        acc = __half2float(g[(size_t)node * 64 + lane]);  // self loop
        int e = 0;
        for (; e + 7 < cn; e += 8) {
            int u[8]; float a[8];
#pragma unroll
            for (int j = 0; j < 8; j++) u[j] = __builtin_nontemporal_load(&csr[st + e + j]);
#pragma unroll
            for (int j = 0; j < 8; j++) a[j] = __half2float(g[(size_t)u[j] * 64 + lane]);
            acc += ((a[0] + a[1]) + (a[2] + a[3])) + ((a[4] + a[5]) + (a[6] + a[7]));
        }
        for (; e + 3 < cn; e += 4) {
            int u0 = __builtin_nontemporal_load(&csr[st + e + 0]);
            int u1 = __builtin_nontemporal_load(&csr[st + e + 1]);
            int u2 = __builtin_nontemporal_load(&csr[st + e + 2]);
            int u3 = __builtin_nontemporal_load(&csr[st + e + 3]);
            float a0 = __half2float(g[(size_t)u0 * 64 + lane]);
            float a1 = __half2float(g[(size_t)u1 * 64 + lane]);
            float a2 = __half2float(g[(size_t)u2 * 64 + lane]);
            float a3 = __half2float(g[(size_t)u3 * 64 + lane]);
            acc += (a0 + a1) + (a2 + a3);
        }
        for (; e < cn; e++) {
            int u = __builtin_nontemporal_load(&csr[st + e]);
            acc += __half2float(g[(size_t)u * 64 + lane]);
        }
    }
    zh[wv][lane] = __float2half_rn(acc);   // wave-private: no barrier
    if (node < n) {
        float t = 0.f;
#pragma unroll
        for (int p = 0; p < 8; p++) {
            uint4 wq = wpk[p][lane];                        // per-lane b128
            uint4 zq = *(const uint4*)&zh[wv][p * 8];       // uniform b128
            t = dot2acc(zq.x, wq.x, t);
            t = dot2acc(zq.y, wq.y, t);
            t = dot2acc(zq.z, wq.z, t);
            t = dot2acc(zq.w, wq.w, t);
        }
        float o = dv * t + bs[lane];
        o = fmaxf(o, 0.f);
        gout[(size_t)node * 64 + lane] = __float2half_rn(dv * o);
    }
}

// ---------------- Layer-4 transform: s4 = g3 @ W4  (dinv cancels exactly) ----------------
__global__ __launch_bounds__(128) void gemm16_kernel(const __half* __restrict__ xin,
                                                     const float* __restrict__ W,
                                                     __half* __restrict__ s, int n) {
    constexpr int DOUT = 16;
    constexpr int ROWS = 128;
    __shared__ float xs[ROWS][65];
    __shared__ float ws[64][DOUT];
    int tid = threadIdx.x;
    int row0 = blockIdx.x * ROWS;
    for (int i = tid; i < 64 * DOUT; i += 128) ws[i / DOUT][i % DOUT] = W[i];
    for (int i = tid; i < ROWS * 16; i += 128) {
        int r = i >> 4, c = (i & 15) * 4;
        float4 v = make_float4(0.f, 0.f, 0.f, 0.f);
        if (row0 + r < n) {
            const __half* hp = xin + (size_t)(row0 + r) * 64 + c;
            float2 f01 = __half22float2(*(const __half2*)hp);
            float2 f23 = __half22float2(*(const __half2*)(hp + 2));
            v = make_float4(f01.x, f01.y, f23.x, f23.y);
        }
        xs[r][c] = v.x; xs[r][c + 1] = v.y; xs[r][c + 2] = v.z; xs[r][c + 3] = v.w;
    }
    __syncthreads();
    int rbase = tid;
    float acc[16];
#pragma unroll
    for (int j = 0; j < 16; j++) acc[j] = 0.f;
    for (int k = 0; k < 64; k++) {
        float xv = xs[rbase][k];
#pragma unroll
        for (int j = 0; j < 4; j++) {
            float4 wv = *(const float4*)&ws[k][j * 4];
            acc[j * 4 + 0] += xv * wv.x;
            acc[j * 4 + 1] += xv * wv.y;
            acc[j * 4 + 2] += xv * wv.z;
            acc[j * 4 + 3] += xv * wv.w;
        }
    }
    int r = row0 + rbase;
    if (r < n) {
        union { ushort u[16]; uint4 q[2]; } pk;
#pragma unroll
        for (int j = 0; j < 16; j++)
            pk.u[j] = __half_as_ushort(__float2half_rn(acc[j]));
        uint4* sp = (uint4*)&s[(size_t)r * DOUT];
        sp[0] = pk.q[0];
        sp[1] = pk.q[1];
    }
}

// ---------------- Layer-4 aggregate: out = dinv*(sum s4) + b4, fp32 ----------------
__global__ __launch_bounds__(256) void agg16_kernel(const __half* __restrict__ s,
                                                    const int* __restrict__ csr,
                                                    const int* __restrict__ start,
                                                    const int* __restrict__ cnt,
                                                    const float* __restrict__ dinv,
                                                    const float* __restrict__ bias,
                                                    float* __restrict__ out, int n) {
    constexpr int D = 16;
    int tid = threadIdx.x;
    int lane = tid & 63;
    int wave = tid >> 6;
    int col = lane % D;
    int grp = lane / D;
    int node = (blockIdx.x * 4 + wave) * 4 + grp;
    if (node >= n) return;
    int st = start[node];
    int cn = cnt[node];
    float acc = __half2float(s[(size_t)node * D + col]);  // self loop
    int e = 0;
    for (; e + 7 < cn; e += 8) {
        int u[8]; float a[8];
#pragma unroll
        for (int j = 0; j < 8; j++) u[j] = __builtin_nontemporal_load(&csr[st + e + j]);
#pragma unroll
        for (int j = 0; j < 8; j++) a[j] = __half2float(s[(size_t)u[j] * D + col]);
        acc += ((a[0] + a[1]) + (a[2] + a[3])) + ((a[4] + a[5]) + (a[6] + a[7]));
    }
    for (; e + 3 < cn; e += 4) {
        int u0 = __builtin_nontemporal_load(&csr[st + e + 0]);
        int u1 = __builtin_nontemporal_load(&csr[st + e + 1]);
        int u2 = __builtin_nontemporal_load(&csr[st + e + 2]);
        int u3 = __builtin_nontemporal_load(&csr[st + e + 3]);
        float a0 = __half2float(s[(size_t)u0 * D + col]);
        float a1 = __half2float(s[(size_t)u1 * D + col]);
        float a2 = __half2float(s[(size_t)u2 * D + col]);
        float a3 = __half2float(s[(size_t)u3 * D + col]);
        acc += (a0 + a1) + (a2 + a3);
    }
    for (; e < cn; e++) {
        int u = __builtin_nontemporal_load(&csr[st + e]);
        acc += __half2float(s[(size_t)u * D + col]);
    }
    float o = dinv[node] * acc + bias[col];
    __builtin_nontemporal_store(o, out + (size_t)node * D + col);
}

// ---------------- launch ----------------

extern "C" void kernel_launch(void* const* d_in, const int* in_sizes, int n_in,
                              void* d_out, int out_size, void* d_ws, size_t ws_size,
                              hipStream_t stream) {
    const float* x  = (const float*)d_in[0];
    const int* ei   = (const int*)d_in[1];
    const float* W1 = (const float*)d_in[2];
    const float* b1 = (const float*)d_in[3];
    const float* W2 = (const float*)d_in[4];
    const float* b2 = (const float*)d_in[5];
    const float* W3 = (const float*)d_in[6];
    const float* b3 = (const float*)d_in[7];
    const float* W4 = (const float*)d_in[8];
    const float* b4 = (const float*)d_in[9];
    const int* src = ei;
    const int* dst = ei + NE;

    // all blocks 128B-aligned; g rows (128B) MUST be 128B-aligned: halves
    // gather line-sectors (R11 finding: FETCH 156->88MB from alignment alone)
    char* w = (char*)d_ws;
    auto alloc = [&](size_t bytes) {
        char* p = w;
        w += (bytes + 127) & ~(size_t)127;
        return p;
    };
    float* dinv  = (float*)alloc((size_t)NN * 4);
    int* cnt     = (int*)alloc((size_t)NN * 4);
    int* start   = (int*)alloc((size_t)NN * 4);
    int* bcur    = (int*)alloc(256 * 4);
    int* csr     = (int*)alloc((size_t)NBKT * SLOT * 4);
    __half* gA   = (__half*)alloc((size_t)NN * 64 * 2);
    __half* gB   = (__half*)alloc((size_t)NN * 64 * 2);
    __half* s4   = (__half*)alloc((size_t)NN * 16 * 2);
    unsigned int* bedges = (unsigned int*)alloc((size_t)NBKT * SLOT * 4);

    zero_small_kernel<<<1, 256, 0, stream>>>(bcur, 256);
    bscatter_kernel<<<(NE + 4095) / 4096, 512, 0, stream>>>(src, dst, bcur, bedges, NE);
    bfill_kernel<<<NBKT, 1024, 0, stream>>>(bedges, bcur, x, start, cnt, dinv, csr, gA);

    const int FB = (NN + 7) / 8;      // 12500 blocks, 1 node/wave
    fused_layer_kernel<<<FB, 512, 0, stream>>>(gA, csr, start, cnt, dinv, W1, b1, gB, NN);
    fused_layer_kernel<<<FB, 512, 0, stream>>>(gB, csr, start, cnt, dinv, W2, b2, gA, NN);
    fused_layer_kernel<<<FB, 512, 0, stream>>>(gA, csr, start, cnt, dinv, W3, b3, gB, NN);

    const int GB = (NN + 127) / 128;
    const int AB16 = (NN + 15) / 16;
    gemm16_kernel<<<GB, 128, 0, stream>>>(gB, W4, s4, NN);
    agg16_kernel<<<AB16, 256, 0, stream>>>(s4, csr, start, cnt, dinv, b4, (float*)d_out, NN);
}